// Round 10
// baseline (116.891 us; speedup 1.0000x reference)
//
#include <hip/hip_runtime.h>

// MLPAttention B=4, LQ=128, LK=1024, D=512, U=256, fp32.
// scores(i,j) = sum_u v_u * tanh(q_iu + k_uj);  tanh(x) = 1 - 2/(1+e^{2x})
// => scores = SV - 2*sum_u v_u/(1 + Eq_iu*Ek_uj),  Eq=e^{2q}, Ek=e^{2k}, SV=sum v
// K1 proj_mfma: fp16 MFMA NT-GEMM, dbuf LDS, epilogue exp(2x) -> Eq, EkT.
// K2 scores_softmax: phase A (j=tid, 256-u loop) + den reduce + NORMALIZED
//    attn write. 256 blocks = full device; XCD swizzle pins batch b to XCD pair.
// K3 attn_value: 64-col V slices (128 MB L2 traffic vs 512 MB fused),
//    8-way in-block K-split, float4 A loads, LDS reduce.

typedef _Float16 half8 __attribute__((ext_vector_type(8)));
typedef float floatx4 __attribute__((ext_vector_type(4)));

#define EQ_OFF   0
#define EKT_OFF  (512 * 256)
#define ATTN_OFF (EKT_OFF + 4 * 256 * 1024)

__global__ __launch_bounds__(256) void proj_mfma(
    const float* __restrict__ query, const float* __restrict__ key,
    const float* __restrict__ W_q, const float* __restrict__ W_k,
    const int* __restrict__ vlen, float* __restrict__ Eq,
    float* __restrict__ EkT) {
  // 64(M) x 64(N) tile, K=512 in 16 steps of BK=32. 256 thr = 4 waves (2x2).
  __shared__ __align__(16) _Float16 As[2][64 * 32];
  __shared__ __align__(16) _Float16 Bs[2][64 * 32];
  const int tid = threadIdx.x;
  const int mb = blockIdx.x;   // 0..7 q-part (m-tiles), 8..71 k-part (j-tiles)
  const int u0 = blockIdx.y * 64;
  const bool qpart = mb < 8;
  const float *Ag, *Bg;
  int kbatch = 0, j0 = 0, m0 = 0;
  if (qpart) {
    m0 = mb * 64;
    Ag = query + (size_t)m0 * 512;   // A rows = query rows (M = m)
    Bg = W_q + (size_t)u0 * 512;     // B rows = W_q rows   (N = u)
  } else {
    const int g0 = (mb - 8) * 64;
    kbatch = g0 >> 10;
    j0 = g0 & 1023;
    if (j0 >= vlen[kbatch]) return;  // fully-masked key tile
    Ag = W_k + (size_t)u0 * 512;     // A rows = W_k rows (M = u)
    Bg = key + (size_t)g0 * 512;     // B rows = key rows (N = j)
  }

  const int lrow = tid >> 2, lkq = (tid & 3) * 8;
  const float* Ags = Ag + lrow * 512 + lkq;
  const float* Bgs = Bg + lrow * 512 + lkq;
  const int lofs = lrow * 32 + lkq;

  const int lane = tid & 63;
  const int wid = tid >> 6;
  const int wm = (wid & 1) * 32, wn = (wid >> 1) * 32;
  const int frow = lane & 15;
  const int fk = (lane >> 4) * 8;

  floatx4 acc[2][2] = {{{0.f, 0.f, 0.f, 0.f}, {0.f, 0.f, 0.f, 0.f}},
                       {{0.f, 0.f, 0.f, 0.f}, {0.f, 0.f, 0.f, 0.f}}};

  float4 ra0 = *(const float4*)Ags;
  float4 ra1 = *(const float4*)(Ags + 4);
  float4 rb0 = *(const float4*)Bgs;
  float4 rb1 = *(const float4*)(Bgs + 4);

  for (int kb = 0; kb < 16; ++kb) {
    const int buf = kb & 1;
    half8 ha, hb;
    ha[0] = (_Float16)ra0.x; ha[1] = (_Float16)ra0.y;
    ha[2] = (_Float16)ra0.z; ha[3] = (_Float16)ra0.w;
    ha[4] = (_Float16)ra1.x; ha[5] = (_Float16)ra1.y;
    ha[6] = (_Float16)ra1.z; ha[7] = (_Float16)ra1.w;
    hb[0] = (_Float16)rb0.x; hb[1] = (_Float16)rb0.y;
    hb[2] = (_Float16)rb0.z; hb[3] = (_Float16)rb0.w;
    hb[4] = (_Float16)rb1.x; hb[5] = (_Float16)rb1.y;
    hb[6] = (_Float16)rb1.z; hb[7] = (_Float16)rb1.w;
    *(half8*)(As[buf] + lofs) = ha;
    *(half8*)(Bs[buf] + lofs) = hb;
    __syncthreads();  // publish buf; reads of this buf were 2 iters ago
    if (kb + 1 < 16) {
      ra0 = *(const float4*)(Ags + (kb + 1) * 32);
      ra1 = *(const float4*)(Ags + (kb + 1) * 32 + 4);
      rb0 = *(const float4*)(Bgs + (kb + 1) * 32);
      rb1 = *(const float4*)(Bgs + (kb + 1) * 32 + 4);
    }
    half8 a0 = *(const half8*)(As[buf] + (wm + frow) * 32 + fk);
    half8 a1 = *(const half8*)(As[buf] + (wm + 16 + frow) * 32 + fk);
    half8 b0 = *(const half8*)(Bs[buf] + (wn + frow) * 32 + fk);
    half8 b1 = *(const half8*)(Bs[buf] + (wn + 16 + frow) * 32 + fk);
    acc[0][0] = __builtin_amdgcn_mfma_f32_16x16x32_f16(a0, b0, acc[0][0], 0, 0, 0);
    acc[0][1] = __builtin_amdgcn_mfma_f32_16x16x32_f16(a0, b1, acc[0][1], 0, 0, 0);
    acc[1][0] = __builtin_amdgcn_mfma_f32_16x16x32_f16(a1, b0, acc[1][0], 0, 0, 0);
    acc[1][1] = __builtin_amdgcn_mfma_f32_16x16x32_f16(a1, b1, acc[1][1], 0, 0, 0);
  }

  // C/D layout: col = lane&15, row = (lane>>4)*4 + reg
  const int rbase = (lane >> 4) * 4;
  const int col = lane & 15;
#pragma unroll
  for (int mi = 0; mi < 2; ++mi)
#pragma unroll
    for (int ni = 0; ni < 2; ++ni)
#pragma unroll
      for (int r = 0; r < 4; ++r) {
        const int R = wm + mi * 16 + rbase + r;   // M index
        const int C = wn + ni * 16 + col;         // N index
        const float e = __expf(2.f * acc[mi][ni][r]);
        if (qpart)
          Eq[(m0 + R) * 256 + u0 + C] = e;
        else
          EkT[kbatch * 262144 + (u0 + R) * 1024 + j0 + C] = e;
      }
}

__global__ __launch_bounds__(1024) void scores_softmax(
    const float* __restrict__ Eq, const float* __restrict__ EkT,
    const float* __restrict__ vvec, const int* __restrict__ valid_len,
    float* __restrict__ attn) {
  // block = (b, 2 query rows); 1024 thr (16 waves); thread = column j.
  __shared__ float4 QV[256];  // (Eq_row0, Eq_row1, -2*v, 0)
  __shared__ float2 red[16];
  const int tid = threadIdx.x;
  // XCD swizzle: bits pick so each XCD pair serves one batch b (EkT[b] hot)
  const int bx = blockIdx.x;
  const int b = (bx >> 1) & 3;
  const int i0 = ((((bx >> 3) << 1) | (bx & 1))) * 2;  // 0..126 even
  const int vl = valid_len[b];

  float vv = 0.f;
  if (tid < 256) {
    vv = vvec[tid];
    QV[tid] = make_float4(Eq[(b * 128 + i0) * 256 + tid],
                          Eq[(b * 128 + i0 + 1) * 256 + tid], -2.f * vv, 0.f);
  }
  float sv = vv;
#pragma unroll
  for (int off = 32; off > 0; off >>= 1) sv += __shfl_xor(sv, off, 64);
  if ((tid & 63) == 0) red[tid >> 6] = make_float2(sv, 0.f);
  __syncthreads();  // publishes QV and red
  float SV = 0.f;
#pragma unroll
  for (int w = 0; w < 16; ++w) SV += red[w].x;

  // ---- scores: p = exp(score) for j = tid (no max-pass; |s| <= ~26) ----
  const int j = tid;
  float p0 = 0.f, p1 = 0.f;
  if (j < vl) {
    float a0 = 0.f, a1 = 0.f;
    const float* kp = EkT + b * 262144 + j;
#pragma unroll 8
    for (int u = 0; u < 256; ++u) {
      float ek = kp[u << 10];  // coalesced 256B/wave per u
      float4 q = QV[u];        // LDS b128 broadcast
      float r0 = __builtin_amdgcn_rcpf(fmaf(q.x, ek, 1.f));
      float r1 = __builtin_amdgcn_rcpf(fmaf(q.y, ek, 1.f));
      a0 = fmaf(q.z, r0, a0);
      a1 = fmaf(q.z, r1, a1);
    }
    p0 = __expf(SV + a0);
    p1 = __expf(SV + a1);
  }

  float2 pp = make_float2(p0, p1);
#pragma unroll
  for (int off = 32; off > 0; off >>= 1) {
    pp.x += __shfl_xor(pp.x, off, 64);
    pp.y += __shfl_xor(pp.y, off, 64);
  }
  __syncthreads();  // prior red reads complete
  if ((tid & 63) == 0) red[tid >> 6] = pp;
  __syncthreads();
  float den0 = 0.f, den1 = 0.f;
#pragma unroll
  for (int w = 0; w < 16; ++w) { den0 += red[w].x; den1 += red[w].y; }

  attn[(b * 128 + i0) * 1024 + j] = p0 * __builtin_amdgcn_rcpf(den0);
  attn[(b * 128 + i0 + 1) * 1024 + j] = p1 * __builtin_amdgcn_rcpf(den1);
}

__global__ __launch_bounds__(512) void attn_value(
    const float* __restrict__ attn, const float* __restrict__ value,
    const int* __restrict__ valid_len, float* __restrict__ out) {
  // grid = 4b x 16 rowgroups x 8 colgroups = 512 blocks, 512 thr (8 waves).
  // Wave w does K-eighth for 8 rows x 64 cols; float4 A loads; LDS reduce.
  // V traffic: 256KB/block x 512 = 128 MB L2 (col-sliced, 4x less than fused).
  __shared__ float red[8][8][64];  // 16 KB
  const int bid = blockIdx.x;
  const int b = bid >> 7;
  const int rg = (bid >> 3) & 15;
  const int cg = bid & 7;
  const int i0 = rg * 8;
  const int w = threadIdx.x >> 6;
  const int lane = threadIdx.x & 63;
  const int vl = valid_len[b];
  const float* A = attn + (b * 128 + i0) * 1024;
  const float* V = value + b * 524288 + cg * 64 + lane;

  float acc[8] = {};
  const int ks = w * 128;
  const int ke = min(ks + 128, vl);
  int k = ks;
  for (; k + 4 <= ke; k += 4) {
    float4 a[8];
#pragma unroll
    for (int r = 0; r < 8; ++r) a[r] = *(const float4*)(A + r * 1024 + k);
    float v0 = V[k * 512];
    float v1 = V[(k + 1) * 512];
    float v2 = V[(k + 2) * 512];
    float v3 = V[(k + 3) * 512];
#pragma unroll
    for (int r = 0; r < 8; ++r) {
      acc[r] = fmaf(a[r].x, v0, acc[r]);
      acc[r] = fmaf(a[r].y, v1, acc[r]);
      acc[r] = fmaf(a[r].z, v2, acc[r]);
      acc[r] = fmaf(a[r].w, v3, acc[r]);
    }
  }
  for (; k < ke; ++k) {
    float vx = V[k * 512];
#pragma unroll
    for (int r = 0; r < 8; ++r) acc[r] = fmaf(A[r * 1024 + k], vx, acc[r]);
  }

#pragma unroll
  for (int r = 0; r < 8; ++r) red[w][r][lane] = acc[r];
  __syncthreads();
  const int r = threadIdx.x >> 6;
  float s = 0.f;
#pragma unroll
  for (int ww = 0; ww < 8; ++ww) s += red[ww][r][lane];
  out[(b * 128 + i0 + r) * 512 + cg * 64 + lane] = s;
}

extern "C" void kernel_launch(void* const* d_in, const int* in_sizes, int n_in,
                              void* d_out, int out_size, void* d_ws, size_t ws_size,
                              hipStream_t stream) {
  const float* query = (const float*)d_in[0];
  const float* key   = (const float*)d_in[1];
  const float* value = (const float*)d_in[2];
  const int*   vlen  = (const int*)d_in[3];
  const float* W_q   = (const float*)d_in[4];
  const float* W_k   = (const float*)d_in[5];
  const float* v     = (const float*)d_in[6];
  float* out = (float*)d_out;

  float* ws   = (float*)d_ws;
  float* Eq   = ws + EQ_OFF;    // 512x256
  float* EkT  = ws + EKT_OFF;   // 4x256x1024
  float* attn = ws + ATTN_OFF;  // 4x128x1024 (normalized)

  proj_mfma<<<dim3(72, 4), 256, 0, stream>>>(query, key, W_q, W_k, vlen, Eq, EkT);
  scores_softmax<<<256, 1024, 0, stream>>>(Eq, EkT, v, vlen, attn);
  attn_value<<<512, 512, 0, stream>>>(attn, value, vlen, out);
}

// Round 11
// 112.109 us; speedup vs baseline: 1.0427x; 1.0427x over previous
//
#include <hip/hip_runtime.h>

// MLPAttention B=4, LQ=128, LK=1024, D=512, U=256, fp32.
// scores(i,j) = sum_u v_u * tanh(q_iu + k_uj);  tanh(x) = 1 - 2/(1+e^{2x})
// => scores = SV - 2*sum_u v_u/(1 + Eq_iu*Ek_uj),  Eq=e^{2q}, Ek=e^{2k}, SV=sum v
// K1 proj_mfma: fp16 MFMA NT-GEMM, epilogue exp(2x) -> Eq, EkT (transposed).
// K2 scores_attn: FUSED scores + softmax + attn@V. No max-pass (|s|<=~26).
//    Phase A: p = exp(score) for 2 rows x 1024 j into LDS (SV hoisted).
//    Phase B: vectorized float4 PV: thread = (4 cols, j-eighth, both rows);
//    16KB LDS partial reduce. attn never touches HBM.
// Best-measured configuration (R8: 114.8 us); R9/R10 structural variants
// (phase-A 2-D split, de-fused PV) were neutral-to-worse. Total is dominated
// by the harness's 268 MB ws re-poison fill (~43 us at ~78% HBM peak).

typedef _Float16 half8 __attribute__((ext_vector_type(8)));
typedef float floatx4 __attribute__((ext_vector_type(4)));

#define EQ_OFF   0
#define EKT_OFF  (512 * 256)

__global__ __launch_bounds__(256) void proj_mfma(
    const float* __restrict__ query, const float* __restrict__ key,
    const float* __restrict__ W_q, const float* __restrict__ W_k,
    const int* __restrict__ vlen, float* __restrict__ Eq,
    float* __restrict__ EkT) {
  // 64(M) x 64(N) tile, K=512 in 16 steps of BK=32. 256 thr = 4 waves (2x2).
  __shared__ __align__(16) _Float16 As[64 * 32];
  __shared__ __align__(16) _Float16 Bs[64 * 32];
  const int tid = threadIdx.x;
  const int mb = blockIdx.x;   // 0..7 q-part (m-tiles), 8..71 k-part (j-tiles)
  const int u0 = blockIdx.y * 64;
  const bool qpart = mb < 8;
  const float *Ag, *Bg;
  int kbatch = 0, j0 = 0, m0 = 0;
  if (qpart) {
    m0 = mb * 64;
    Ag = query + (size_t)m0 * 512;   // A rows = query rows (M = m)
    Bg = W_q + (size_t)u0 * 512;     // B rows = W_q rows   (N = u)
  } else {
    const int g0 = (mb - 8) * 64;
    kbatch = g0 >> 10;
    j0 = g0 & 1023;
    if (j0 >= vlen[kbatch]) return;  // fully-masked key tile
    Ag = W_k + (size_t)u0 * 512;     // A rows = W_k rows (M = u)
    Bg = key + (size_t)g0 * 512;     // B rows = key rows (N = j)
  }

  const int lrow = tid >> 2, lkq = (tid & 3) * 8;
  const float* Ags = Ag + lrow * 512 + lkq;
  const float* Bgs = Bg + lrow * 512 + lkq;
  _Float16* Ads = As + lrow * 32 + lkq;
  _Float16* Bds = Bs + lrow * 32 + lkq;

  const int lane = tid & 63;
  const int wid = tid >> 6;
  const int wm = (wid & 1) * 32, wn = (wid >> 1) * 32;
  const int frow = lane & 15;
  const int fk = (lane >> 4) * 8;

  floatx4 acc[2][2] = {{{0.f, 0.f, 0.f, 0.f}, {0.f, 0.f, 0.f, 0.f}},
                       {{0.f, 0.f, 0.f, 0.f}, {0.f, 0.f, 0.f, 0.f}}};

  float4 ra0 = *(const float4*)Ags;
  float4 ra1 = *(const float4*)(Ags + 4);
  float4 rb0 = *(const float4*)Bgs;
  float4 rb1 = *(const float4*)(Bgs + 4);

  for (int kb = 0; kb < 16; ++kb) {
    half8 ha, hb;
    ha[0] = (_Float16)ra0.x; ha[1] = (_Float16)ra0.y;
    ha[2] = (_Float16)ra0.z; ha[3] = (_Float16)ra0.w;
    ha[4] = (_Float16)ra1.x; ha[5] = (_Float16)ra1.y;
    ha[6] = (_Float16)ra1.z; ha[7] = (_Float16)ra1.w;
    hb[0] = (_Float16)rb0.x; hb[1] = (_Float16)rb0.y;
    hb[2] = (_Float16)rb0.z; hb[3] = (_Float16)rb0.w;
    hb[4] = (_Float16)rb1.x; hb[5] = (_Float16)rb1.y;
    hb[6] = (_Float16)rb1.z; hb[7] = (_Float16)rb1.w;
    __syncthreads();  // prior iter's fragment reads complete
    *(half8*)Ads = ha;
    *(half8*)Bds = hb;
    __syncthreads();
    if (kb + 1 < 16) {
      ra0 = *(const float4*)(Ags + (kb + 1) * 32);
      ra1 = *(const float4*)(Ags + (kb + 1) * 32 + 4);
      rb0 = *(const float4*)(Bgs + (kb + 1) * 32);
      rb1 = *(const float4*)(Bgs + (kb + 1) * 32 + 4);
    }
    half8 a0 = *(const half8*)(As + (wm + frow) * 32 + fk);
    half8 a1 = *(const half8*)(As + (wm + 16 + frow) * 32 + fk);
    half8 b0 = *(const half8*)(Bs + (wn + frow) * 32 + fk);
    half8 b1 = *(const half8*)(Bs + (wn + 16 + frow) * 32 + fk);
    acc[0][0] = __builtin_amdgcn_mfma_f32_16x16x32_f16(a0, b0, acc[0][0], 0, 0, 0);
    acc[0][1] = __builtin_amdgcn_mfma_f32_16x16x32_f16(a0, b1, acc[0][1], 0, 0, 0);
    acc[1][0] = __builtin_amdgcn_mfma_f32_16x16x32_f16(a1, b0, acc[1][0], 0, 0, 0);
    acc[1][1] = __builtin_amdgcn_mfma_f32_16x16x32_f16(a1, b1, acc[1][1], 0, 0, 0);
  }

  // C/D layout: col = lane&15, row = (lane>>4)*4 + reg
  const int rbase = (lane >> 4) * 4;
  const int col = lane & 15;
#pragma unroll
  for (int mi = 0; mi < 2; ++mi)
#pragma unroll
    for (int ni = 0; ni < 2; ++ni)
#pragma unroll
      for (int r = 0; r < 4; ++r) {
        const int R = wm + mi * 16 + rbase + r;   // M index
        const int C = wn + ni * 16 + col;         // N index
        const float e = __expf(2.f * acc[mi][ni][r]);
        if (qpart)
          Eq[(m0 + R) * 256 + u0 + C] = e;
        else
          EkT[kbatch * 262144 + (u0 + R) * 1024 + j0 + C] = e;
      }
}

__global__ __launch_bounds__(1024) void scores_attn(
    const float* __restrict__ Eq, const float* __restrict__ EkT,
    const float* __restrict__ vvec, const int* __restrict__ valid_len,
    const float* __restrict__ value, float* __restrict__ out) {
  // block = (b, 2 query rows); 1024 thr (16 waves).
  __shared__ float4 QV[256];          // (Eq_row0, Eq_row1, -2*v, 0)
  __shared__ float P0[1024];          // unnormalized numerators, row i0
  __shared__ float P1[1024];          // row i0+1
  __shared__ float2 red[16];
  __shared__ float4 red2[8][2][128];  // 16KB phase-B partials
  const int tid = threadIdx.x;
  const int b = blockIdx.x >> 6;
  const int i0 = (blockIdx.x & 63) * 2;
  const int vl = valid_len[b];

  // stage QV; reduce SV = sum_u v_u once (hoisted out of the u-loop)
  float vv = 0.f;
  if (tid < 256) {
    vv = vvec[tid];
    QV[tid] = make_float4(Eq[(b * 128 + i0) * 256 + tid],
                          Eq[(b * 128 + i0 + 1) * 256 + tid], -2.f * vv, 0.f);
  }
  float sv = vv;
#pragma unroll
  for (int off = 32; off > 0; off >>= 1) sv += __shfl_xor(sv, off, 64);
  if ((tid & 63) == 0) red[tid >> 6] = make_float2(sv, 0.f);
  __syncthreads();  // publishes QV and red
  float SV = 0.f;
#pragma unroll
  for (int w = 0; w < 16; ++w) SV += red[w].x;

  // ---- Phase A: p = exp(score) for j = tid (no max-pass; |s| <= ~26) ----
  const int j = tid;
  float p0 = 0.f, p1 = 0.f;
  if (j < vl) {
    float a0 = 0.f, a1 = 0.f;
    const float* kp = EkT + b * 262144 + j;
#pragma unroll 8
    for (int u = 0; u < 256; ++u) {
      float ek = kp[u << 10];  // coalesced 256B/wave per u
      float4 q = QV[u];        // LDS b128 broadcast (cheap)
      float r0 = __builtin_amdgcn_rcpf(fmaf(q.x, ek, 1.f));
      float r1 = __builtin_amdgcn_rcpf(fmaf(q.y, ek, 1.f));
      a0 = fmaf(q.z, r0, a0);
      a1 = fmaf(q.z, r1, a1);
    }
    p0 = __expf(SV + a0);
    p1 = __expf(SV + a1);
  }
  P0[j] = p0;
  P1[j] = p1;

  // fused den reduce for both rows
  float2 pp = make_float2(p0, p1);
#pragma unroll
  for (int off = 32; off > 0; off >>= 1) {
    pp.x += __shfl_xor(pp.x, off, 64);
    pp.y += __shfl_xor(pp.y, off, 64);
  }
  __syncthreads();  // red[] reuse: prior reads done
  if ((tid & 63) == 0) red[tid >> 6] = pp;
  __syncthreads();  // publishes P0/P1 and red
  float den0 = 0.f, den1 = 0.f;
#pragma unroll
  for (int w = 0; w < 16; ++w) { den0 += red[w].x; den1 += red[w].y; }

  // ---- Phase B: thread = (4 cols, j-eighth), both rows share V loads ----
  const int cg = tid & 127;        // col group: c = cg*4
  const int jq = tid >> 7;         // 0..7: j-range [jq*128, jq*128+128)
  const float* Vb = value + b * 524288 + cg * 4;
  float4 acc0 = make_float4(0.f, 0.f, 0.f, 0.f);
  float4 acc1 = make_float4(0.f, 0.f, 0.f, 0.f);
  const int js = jq * 128;
  const int je = min(js + 128, vl);
  for (int j4 = js; j4 < je; j4 += 4) {  // full 4-body safe: P==0 beyond vl
    float4 q0 = *(const float4*)(P0 + j4);  // broadcast across wave
    float4 q1 = *(const float4*)(P1 + j4);
#pragma unroll
    for (int t = 0; t < 4; ++t) {
      float4 v4 = *(const float4*)(Vb + (j4 + t) * 512);  // 1KB/wave
      float w0 = t == 0 ? q0.x : t == 1 ? q0.y : t == 2 ? q0.z : q0.w;
      float w1 = t == 0 ? q1.x : t == 1 ? q1.y : t == 2 ? q1.z : q1.w;
      acc0.x = fmaf(w0, v4.x, acc0.x); acc0.y = fmaf(w0, v4.y, acc0.y);
      acc0.z = fmaf(w0, v4.z, acc0.z); acc0.w = fmaf(w0, v4.w, acc0.w);
      acc1.x = fmaf(w1, v4.x, acc1.x); acc1.y = fmaf(w1, v4.y, acc1.y);
      acc1.z = fmaf(w1, v4.z, acc1.z); acc1.w = fmaf(w1, v4.w, acc1.w);
    }
  }
  red2[jq][0][cg] = acc0;
  red2[jq][1][cg] = acc1;
  __syncthreads();

  if (tid < 256) {
    const int r = tid >> 7, cg2 = tid & 127;
    float4 s = make_float4(0.f, 0.f, 0.f, 0.f);
#pragma unroll
    for (int q = 0; q < 8; ++q) {
      float4 x = red2[q][r][cg2];
      s.x += x.x; s.y += x.y; s.z += x.z; s.w += x.w;
    }
    const float rden = __builtin_amdgcn_rcpf(r ? den1 : den0);
    s.x *= rden; s.y *= rden; s.z *= rden; s.w *= rden;
    *(float4*)(out + (b * 128 + i0 + r) * 512 + cg2 * 4) = s;
  }
}

extern "C" void kernel_launch(void* const* d_in, const int* in_sizes, int n_in,
                              void* d_out, int out_size, void* d_ws, size_t ws_size,
                              hipStream_t stream) {
  const float* query = (const float*)d_in[0];
  const float* key   = (const float*)d_in[1];
  const float* value = (const float*)d_in[2];
  const int*   vlen  = (const int*)d_in[3];
  const float* W_q   = (const float*)d_in[4];
  const float* W_k   = (const float*)d_in[5];
  const float* v     = (const float*)d_in[6];
  float* out = (float*)d_out;

  float* ws  = (float*)d_ws;
  float* Eq  = ws + EQ_OFF;    // 512x256
  float* EkT = ws + EKT_OFF;   // 4x256x1024

  proj_mfma<<<dim3(72, 4), 256, 0, stream>>>(query, key, W_q, W_k, vlen, Eq, EkT);
  scores_attn<<<256, 1024, 0, stream>>>(Eq, EkT, v, vlen, value, out);
}